// Round 10
// baseline (44.469 us; speedup 1.0000x reference)
//
#include <hip/hip_runtime.h>

// ---------------------------------------------------------------------------
// LeNet5-KAN on MI355X.  R10: R9 conv12 structure (proven, 4 blocks/CU) with
// fc1/fc2/fc3 fused as per-block epilogue (h2 never leaves LDS).
// MFMA f16 in / f32 accum; avg-pool folded into weights (stride-2 conv6x6).
//
// GEMM view per conv:  out[p][o] = sum_K feat16[elem(p,tap)][k] * W[tap,k][o]
//   K = taps(36) x kpad(16): k0..7 = cubic B-spline bases, k8 = relu, rest 0.
//   A-frag: lane&15 = out px, lane>>4 = k-group (16B ds_read_b128)
//   B-frag: lane&15 = o,     lane>>4 = same k-group (16B global load, L2)
//   C     : col = lane&15 (o), row = (lane>>4)*4 + reg
// feat LDS chunks (16B) XOR-swizzled: ch ^= (ch>>3)&7.
// ---------------------------------------------------------------------------

typedef _Float16 f16;
typedef f16 f16x8 __attribute__((ext_vector_type(8)));
typedef float f32x4 __attribute__((ext_vector_type(4)));

#define ONE_SIXTH 0.16666666666666666f

__device__ __forceinline__ void spline9(float v, float* __restrict__ f) {
    float u  = 2.5f * v + 5.5f;
    bool valid = (u >= 0.0f) && (u < 11.0f);
    float fi = floorf(u);
    int   i  = (int)fi;
    float w  = u - fi;
    float omw = 1.0f - w;
    float w2 = w * w, w3 = w2 * w;
    float c0 = omw * omw * omw * ONE_SIXTH;
    float c1 = (3.0f * w3 - 6.0f * w2 + 4.0f) * ONE_SIXTH;
    float c2 = (-3.0f * w3 + 3.0f * w2 + 3.0f * w + 1.0f) * ONE_SIXTH;
    float c3 = w3 * ONE_SIXTH;
    int j0 = i - 3;
#pragma unroll
    for (int j = 0; j < 8; ++j) {
        int d = j - j0;
        float val = (d == 0) ? c0 : (d == 1) ? c1 : (d == 2) ? c2 : (d == 3) ? c3 : 0.0f;
        f[j] = valid ? val : 0.0f;
    }
    f[8] = fmaxf(v, 0.0f);
}

// two 16B chunks: c0 = bases[0..7] as f16, c1 = {relu, 0 x7}
__device__ __forceinline__ void spline_chunks(float v, uint4& u0, uint4& u1) {
    float f[9];
    spline9(v, f);
    union { f16 h[8]; uint4 u; } a, b;
#pragma unroll
    for (int j = 0; j < 8; ++j) a.h[j] = (f16)f[j];
    b.u.x = 0u; b.u.y = 0u; b.u.z = 0u; b.u.w = 0u;
    b.h[0] = (f16)f[8];
    u0 = a.u; u1 = b.u;
}

// ---------------------------------------------------------------------------
// K0: build pooled-conv weights, f16.
// W1g[(tap*16 + o)*16 + k], tap<36, o<16 (6 valid), k<16 (9 valid)
// W2g[((c*36 + tap)*16 + o)*16 + k], c<6
// w'[ey][ex] = 0.25 * sum_{a,b in {0,1}, 0<=ey-a<5, 0<=ex-b<5} w[ey-a][ex-b]
// ---------------------------------------------------------------------------
__global__ __launch_bounds__(256) void k_prep(
    const float* __restrict__ c1_bw, const float* __restrict__ c1_sw,
    const float* __restrict__ c1_sc,
    const float* __restrict__ c2_bw, const float* __restrict__ c2_sw,
    const float* __restrict__ c2_sc,
    f16* __restrict__ W1g, f16* __restrict__ W2g)
{
    int t = blockIdx.x * 256 + threadIdx.x;
    if (t < 9216) {
        int tap = t >> 8, r = t & 255;
        int o = r >> 4, k = r & 15;
        float val = 0.0f;
        if (o < 6 && k < 9) {
            int ey = tap / 6, ex = tap - 6 * ey;
            float s = 0.0f;
            for (int a = 0; a < 2; ++a) {
                for (int b = 0; b < 2; ++b) {
                    int dy = ey - a, dx = ex - b;
                    if (dy >= 0 && dy < 5 && dx >= 0 && dx < 5) {
                        int idx = o * 25 + dy * 5 + dx;
                        s += (k == 8) ? c1_bw[idx] : c1_sw[idx * 8 + k] * c1_sc[idx];
                    }
                }
            }
            val = 0.25f * s;
        }
        W1g[t] = (f16)val;
    }
    if (t < 55296) {
        int c = t / 9216, r = t - c * 9216;
        int tap = r >> 8, rr = r & 255;
        int o = rr >> 4, k = rr & 15;
        float val = 0.0f;
        if (k < 9) {
            int ey = tap / 6, ex = tap - 6 * ey;
            float s = 0.0f;
            for (int a = 0; a < 2; ++a) {
                for (int b = 0; b < 2; ++b) {
                    int dy = ey - a, dx = ex - b;
                    if (dy >= 0 && dy < 5 && dx >= 0 && dx < 5) {
                        int idx = o * 150 + c * 25 + dy * 5 + dx;
                        s += (k == 8) ? c2_bw[idx] : c2_sw[idx * 8 + k] * c2_sc[idx];
                    }
                }
            }
            val = 0.25f * s;
        }
        W2g[t] = (f16)val;
    }
}

// ---------------------------------------------------------------------------
// K1: fused conv1+pool -> conv2+pool -> fc. One block = 1 image, 192 thr.
// A: spline-stage x.  B: conv1 MFMA -> h1 LDS.  C: spline-stage h1.
// D: conv2 MFMA (K 3-way split, dual acc) -> reduce -> h2 LDS.
// E: fc1(relu)->fc2(relu)->fc3 -> out (weights f32 from L2).
// ---------------------------------------------------------------------------
__global__ __launch_bounds__(192, 3) void k_conv12(
    const float* __restrict__ x, const f16* __restrict__ W1g,
    const f16* __restrict__ W2g,
    const float* __restrict__ w1, const float* __restrict__ b1,
    const float* __restrict__ w2, const float* __restrict__ b2,
    const float* __restrict__ w3, const float* __restrict__ b3,
    float* __restrict__ out)
{
    __shared__ uint4  feat[1728];    // A: 1568 used; C: 1728 used (aliased)
    __shared__ float  h1l[864];      // conv1 output [o][144] f32
    __shared__ float4 rbuf[2][64];   // conv2 partial sums (waves 1,2)
    __shared__ float  h2l[256];      // conv2 output (fc input)
    __shared__ float  a1[120];
    __shared__ float  a2[84];

    const int img = blockIdx.x;
    const int tid = threadIdx.x;
    const int lane = tid & 63, wv = tid >> 6;
    const int ln15 = lane & 15, g = lane >> 4;
    const int gh = g & 1, gt = g >> 1;

    // ---- Phase A: stage feat(x) ----
    for (int e = tid; e < 784; e += 192) {
        uint4 u0, u1;
        spline_chunks(x[img * 784 + e], u0, u1);
        int ch = e * 2;
        int q = (ch >> 3) & 7;
        feat[ch ^ q] = u0;
        feat[(ch + 1) ^ q] = u1;
    }
    __syncthreads();

    // ---- Phase B: conv1 ----
    {
        int ebase[3];
#pragma unroll
        for (int t = 0; t < 3; ++t) {
            int p = (wv * 3 + t) * 16 + ln15;
            int py = p / 12, px = p - py * 12;
            ebase[t] = py * 56 + px * 2;            // (2py)*28 + 2px
        }
        const f16* bptr = W1g + (gt * 16 + ln15) * 16 + gh * 8;
        f16x8 bfrag = *(const f16x8*)bptr;
        f32x4 acc[3] = {{0,0,0,0},{0,0,0,0},{0,0,0,0}};

        for (int kc = 0; kc < 18; ++kc) {
            int tap = kc * 2 + gt;
            int ey = (tap * 171) >> 10, ex = tap - ey * 6;
            int eoff = ey * 28 + ex;
            f16x8 bcur = bfrag;
            bptr += 512;
            bfrag = *(const f16x8*)bptr;            // overreads into W2g: safe
#pragma unroll
            for (int t = 0; t < 3; ++t) {
                int ch = (ebase[t] + eoff) * 2 + gh;
                ch ^= (ch >> 3) & 7;
                f16x8 afrag = *(const f16x8*)(&feat[ch]);
                acc[t] = __builtin_amdgcn_mfma_f32_16x16x32_f16(afrag, bcur, acc[t], 0, 0, 0);
            }
        }
        if (ln15 < 6) {
#pragma unroll
            for (int t = 0; t < 3; ++t) {
                int p0 = (wv * 3 + t) * 16 + g * 4;     // row = g*4 + reg
                *(float4*)&h1l[ln15 * 144 + p0] =
                    make_float4(acc[t][0], acc[t][1], acc[t][2], acc[t][3]);
            }
        }
    }
    __syncthreads();    // feat reads done + h1l visible

    // ---- Phase C: stage feat(h1) ----
    for (int e = tid; e < 864; e += 192) {
        uint4 u0, u1;
        spline_chunks(h1l[e], u0, u1);
        int ch = e * 2;
        int q = (ch >> 3) & 7;
        feat[ch ^ q] = u0;
        feat[(ch + 1) ^ q] = u1;
    }
    __syncthreads();

    // ---- Phase D: conv2, K split over 3 waves, dual acc chains ----
    {
        const int py = ln15 >> 2, px = ln15 & 3;
        const int epx = py * 24 + px * 2;           // (2py)*12 + 2px
        const int kk0 = wv * 36;
        const f16* bptr = W2g + ((kk0 * 2 + gt) * 16 + ln15) * 16 + gh * 8;
        f16x8 bfrag = *(const f16x8*)bptr;
        f32x4 accA = {0, 0, 0, 0}, accB = {0, 0, 0, 0};

        for (int i = 0; i < 36; i += 2) {
#pragma unroll
            for (int s = 0; s < 2; ++s) {
                int kk = kk0 + i + s;
                int c = kk / 18, tk = kk - c * 18;
                int tap = tk * 2 + gt;
                int ey = (tap * 171) >> 10, ex = tap - ey * 6;
                f16x8 bcur = bfrag;
                bptr += 512;
                bfrag = *(const f16x8*)bptr;        // overread past W2g: padded
                int elem = c * 144 + epx + ey * 12 + ex;
                int ch = elem * 2 + gh;
                ch ^= (ch >> 3) & 7;
                f16x8 afrag = *(const f16x8*)(&feat[ch]);
                if (s == 0)
                    accA = __builtin_amdgcn_mfma_f32_16x16x32_f16(afrag, bcur, accA, 0, 0, 0);
                else
                    accB = __builtin_amdgcn_mfma_f32_16x16x32_f16(afrag, bcur, accB, 0, 0, 0);
            }
        }
        f32x4 acc = accA + accB;

        if (wv) rbuf[wv - 1][lane] = make_float4(acc[0], acc[1], acc[2], acc[3]);
        __syncthreads();
        if (wv == 0) {
            float4 r0 = rbuf[0][lane], r1 = rbuf[1][lane];
            *(float4*)&h2l[ln15 * 16 + g * 4] =
                make_float4(acc[0] + r0.x + r1.x, acc[1] + r0.y + r1.y,
                            acc[2] + r0.z + r1.z, acc[3] + r0.w + r1.w);
        }
    }
    __syncthreads();

    // ---- Phase E: fc chain (f32 weights streamed from L2) ----
    if (tid < 120) {
        const float* w = w1 + tid * 256;
        float s = 0.0f;
#pragma unroll 8
        for (int k = 0; k < 64; ++k) {
            float4 wv4 = ((const float4*)w)[k];
            float4 xv = *(const float4*)(&h2l[k * 4]);
            s += wv4.x * xv.x + wv4.y * xv.y + wv4.z * xv.z + wv4.w * xv.w;
        }
        a1[tid] = fmaxf(s + b1[tid], 0.0f);
    }
    __syncthreads();

    if (tid < 84) {
        const float* w = w2 + tid * 120;
        float s = 0.0f;
#pragma unroll
        for (int k = 0; k < 30; ++k) {
            float4 wv4 = ((const float4*)w)[k];
            float4 xv = *(const float4*)(&a1[k * 4]);
            s += wv4.x * xv.x + wv4.y * xv.y + wv4.z * xv.z + wv4.w * xv.w;
        }
        a2[tid] = fmaxf(s + b2[tid], 0.0f);
    }
    __syncthreads();

    if (tid < 62) {
        const float* w = w3 + tid * 84;
        float s = 0.0f;
#pragma unroll
        for (int k = 0; k < 21; ++k) {
            float4 wv4 = ((const float4*)w)[k];
            float4 xv = *(const float4*)(&a2[k * 4]);
            s += wv4.x * xv.x + wv4.y * xv.y + wv4.z * xv.z + wv4.w * xv.w;
        }
        out[img * 62 + tid] = s + b3[tid];
    }
}

// ---------------------------------------------------------------------------
extern "C" void kernel_launch(void* const* d_in, const int* in_sizes, int n_in,
                              void* d_out, int out_size, void* d_ws, size_t ws_size,
                              hipStream_t stream)
{
    (void)in_sizes; (void)n_in; (void)out_size; (void)ws_size;
    const float* x      = (const float*)d_in[0];
    const float* c1_bw  = (const float*)d_in[1];
    const float* c1_sw  = (const float*)d_in[2];
    const float* c1_sc  = (const float*)d_in[3];
    const float* c2_bw  = (const float*)d_in[4];
    const float* c2_sw  = (const float*)d_in[5];
    const float* c2_sc  = (const float*)d_in[6];
    const float* fc1_w  = (const float*)d_in[7];
    const float* fc1_b  = (const float*)d_in[8];
    const float* fc2_w  = (const float*)d_in[9];
    const float* fc2_b  = (const float*)d_in[10];
    const float* fc3_w  = (const float*)d_in[11];
    const float* fc3_b  = (const float*)d_in[12];
    float* out = (float*)d_out;

    char* wsb = (char*)d_ws;
    f16* W1g = (f16*)(wsb);                    //  9216 f16 = 18432 B
    f16* W2g = (f16*)(wsb + 18432);            // 55296 f16 = 110592 B (+pad)

    hipLaunchKernelGGL(k_prep, dim3(256), dim3(256), 0, stream,
                       c1_bw, c1_sw, c1_sc, c2_bw, c2_sw, c2_sc, W1g, W2g);
    hipLaunchKernelGGL(k_conv12, dim3(1024), dim3(192), 0, stream,
                       x, W1g, W2g,
                       fc1_w, fc1_b, fc2_w, fc2_b, fc3_w, fc3_b, out);
}

// Round 11
// 39.603 us; speedup vs baseline: 1.1229x; 1.1229x over previous
//
#include <hip/hip_runtime.h>

// ---------------------------------------------------------------------------
// LeNet5-KAN on MI355X.  R11: R9 structure (proven 39.8us) + 4-deep B-frag
// register prefetch (full unroll, wreg[kc&3] rotation) + issue-first staging
// loads in phases A/C.  fc separate at 512 blocks (R9's win).
// MFMA f16 in / f32 accum; avg-pool folded into weights (stride-2 conv6x6).
//
// GEMM view per conv:  out[p][o] = sum_K feat16[elem(p,tap)][k] * W[tap,k][o]
//   K = taps(36) x kpad(16): k0..7 = cubic B-spline bases, k8 = relu, rest 0.
//   A-frag: lane&15 = out px, lane>>4 = k-group (16B ds_read_b128)
//   B-frag: lane&15 = o,     lane>>4 = same k-group (16B global load, L2)
//   C     : col = lane&15 (o), row = (lane>>4)*4 + reg
// feat LDS chunks (16B) XOR-swizzled: ch ^= (ch>>3)&7.
// ---------------------------------------------------------------------------

typedef _Float16 f16;
typedef f16 f16x8 __attribute__((ext_vector_type(8)));
typedef float f32x4 __attribute__((ext_vector_type(4)));

#define ONE_SIXTH 0.16666666666666666f

__device__ __forceinline__ void spline9(float v, float* __restrict__ f) {
    float u  = 2.5f * v + 5.5f;
    bool valid = (u >= 0.0f) && (u < 11.0f);
    float fi = floorf(u);
    int   i  = (int)fi;
    float w  = u - fi;
    float omw = 1.0f - w;
    float w2 = w * w, w3 = w2 * w;
    float c0 = omw * omw * omw * ONE_SIXTH;
    float c1 = (3.0f * w3 - 6.0f * w2 + 4.0f) * ONE_SIXTH;
    float c2 = (-3.0f * w3 + 3.0f * w2 + 3.0f * w + 1.0f) * ONE_SIXTH;
    float c3 = w3 * ONE_SIXTH;
    int j0 = i - 3;
#pragma unroll
    for (int j = 0; j < 8; ++j) {
        int d = j - j0;
        float val = (d == 0) ? c0 : (d == 1) ? c1 : (d == 2) ? c2 : (d == 3) ? c3 : 0.0f;
        f[j] = valid ? val : 0.0f;
    }
    f[8] = fmaxf(v, 0.0f);
}

// two 16B chunks: c0 = bases[0..7] as f16, c1 = {relu, 0 x7}
__device__ __forceinline__ void spline_chunks(float v, uint4& u0, uint4& u1) {
    float f[9];
    spline9(v, f);
    union { f16 h[8]; uint4 u; } a, b;
#pragma unroll
    for (int j = 0; j < 8; ++j) a.h[j] = (f16)f[j];
    b.u.x = 0u; b.u.y = 0u; b.u.z = 0u; b.u.w = 0u;
    b.h[0] = (f16)f[8];
    u0 = a.u; u1 = b.u;
}

// ---------------------------------------------------------------------------
// K0: build pooled-conv weights, f16.
// W1g[(tap*16 + o)*16 + k], tap<36, o<16 (6 valid), k<16 (9 valid)
// W2g[((c*36 + tap)*16 + o)*16 + k], c<6
// w'[ey][ex] = 0.25 * sum_{a,b in {0,1}, 0<=ey-a<5, 0<=ex-b<5} w[ey-a][ex-b]
// ---------------------------------------------------------------------------
__global__ __launch_bounds__(256) void k_prep(
    const float* __restrict__ c1_bw, const float* __restrict__ c1_sw,
    const float* __restrict__ c1_sc,
    const float* __restrict__ c2_bw, const float* __restrict__ c2_sw,
    const float* __restrict__ c2_sc,
    f16* __restrict__ W1g, f16* __restrict__ W2g)
{
    int t = blockIdx.x * 256 + threadIdx.x;
    if (t < 9216) {
        int tap = t >> 8, r = t & 255;
        int o = r >> 4, k = r & 15;
        float val = 0.0f;
        if (o < 6 && k < 9) {
            int ey = tap / 6, ex = tap - 6 * ey;
            float s = 0.0f;
            for (int a = 0; a < 2; ++a) {
                for (int b = 0; b < 2; ++b) {
                    int dy = ey - a, dx = ex - b;
                    if (dy >= 0 && dy < 5 && dx >= 0 && dx < 5) {
                        int idx = o * 25 + dy * 5 + dx;
                        s += (k == 8) ? c1_bw[idx] : c1_sw[idx * 8 + k] * c1_sc[idx];
                    }
                }
            }
            val = 0.25f * s;
        }
        W1g[t] = (f16)val;
    }
    if (t < 55296) {
        int c = t / 9216, r = t - c * 9216;
        int tap = r >> 8, rr = r & 255;
        int o = rr >> 4, k = rr & 15;
        float val = 0.0f;
        if (k < 9) {
            int ey = tap / 6, ex = tap - 6 * ey;
            float s = 0.0f;
            for (int a = 0; a < 2; ++a) {
                for (int b = 0; b < 2; ++b) {
                    int dy = ey - a, dx = ex - b;
                    if (dy >= 0 && dy < 5 && dx >= 0 && dx < 5) {
                        int idx = o * 150 + c * 25 + dy * 5 + dx;
                        s += (k == 8) ? c2_bw[idx] : c2_sw[idx * 8 + k] * c2_sc[idx];
                    }
                }
            }
            val = 0.25f * s;
        }
        W2g[t] = (f16)val;
    }
}

// ---------------------------------------------------------------------------
// K1: fused conv1+pool -> conv2+pool. One block = 1 image, 192 thr = 3 waves.
// A: stage feat(x) (loads issued first, 5 in flight).
// B: conv1 MFMA, 18 kc fully unrolled, 4-deep wreg rotation.
// C: stage feat(h1) (ds reads issued first).
// D: conv2 MFMA, 36 kc fully unrolled, 4-deep rotation, dual acc chains.
// ---------------------------------------------------------------------------
__global__ __launch_bounds__(192, 3) void k_conv12(
    const float* __restrict__ x, const f16* __restrict__ W1g,
    const f16* __restrict__ W2g, float* __restrict__ h2)
{
    __shared__ uint4  feat[1728];    // A: 1568 used; C: 1728 used (aliased)
    __shared__ float  h1l[864];      // conv1 output [o][144] f32
    __shared__ float4 rbuf[2][64];   // conv2 partial sums (waves 1,2)

    const int img = blockIdx.x;
    const int tid = threadIdx.x;
    const int lane = tid & 63, wv = tid >> 6;
    const int ln15 = lane & 15, g = lane >> 4;
    const int gh = g & 1, gt = g >> 1;

    // ---- Phase A: stage feat(x); all 5 global loads issued first ----
    {
        float xv[5];
#pragma unroll
        for (int p = 0; p < 5; ++p) {
            int e = tid + p * 192;
            xv[p] = x[img * 784 + (e < 784 ? e : 783)];
        }
#pragma unroll
        for (int p = 0; p < 5; ++p) {
            int e = tid + p * 192;
            if (e < 784) {
                uint4 u0, u1;
                spline_chunks(xv[p], u0, u1);
                int ch = e * 2;
                int q = (ch >> 3) & 7;
                feat[ch ^ q] = u0;
                feat[(ch + 1) ^ q] = u1;
            }
        }
    }
    __syncthreads();

    // ---- Phase B: conv1, 18 kc unrolled, 4-deep prefetch ----
    {
        int ebase[3];
#pragma unroll
        for (int t = 0; t < 3; ++t) {
            int p = (wv * 3 + t) * 16 + ln15;
            int py = p / 12, px = p - py * 12;
            ebase[t] = py * 56 + px * 2;            // (2py)*28 + 2px
        }
        const f16* bbase = W1g + (gt * 16 + ln15) * 16 + gh * 8;  // + kc*512
        f16x8 wreg[4];
#pragma unroll
        for (int i = 0; i < 4; ++i)
            wreg[i] = *(const f16x8*)(bbase + i * 512);

        f32x4 acc[3] = {{0,0,0,0},{0,0,0,0},{0,0,0,0}};

#pragma unroll
        for (int kc = 0; kc < 18; ++kc) {
            f16x8 bcur = wreg[kc & 3];
            wreg[kc & 3] = *(const f16x8*)(bbase + (kc + 4) * 512); // overreads into W2g: safe
            int tap = kc * 2 + gt;
            int ey = (tap * 171) >> 10, ex = tap - ey * 6;
            int eoff = ey * 28 + ex;
#pragma unroll
            for (int t = 0; t < 3; ++t) {
                int ch = (ebase[t] + eoff) * 2 + gh;
                ch ^= (ch >> 3) & 7;
                f16x8 afrag = *(const f16x8*)(&feat[ch]);
                acc[t] = __builtin_amdgcn_mfma_f32_16x16x32_f16(afrag, bcur, acc[t], 0, 0, 0);
            }
        }
        if (ln15 < 6) {
#pragma unroll
            for (int t = 0; t < 3; ++t) {
                int p0 = (wv * 3 + t) * 16 + g * 4;     // row = g*4 + reg
                *(float4*)&h1l[ln15 * 144 + p0] =
                    make_float4(acc[t][0], acc[t][1], acc[t][2], acc[t][3]);
            }
        }
    }
    __syncthreads();    // feat reads done + h1l visible

    // ---- Phase C: stage feat(h1); ds reads issued first ----
    {
        float hv[5];
#pragma unroll
        for (int p = 0; p < 5; ++p) {
            int e = tid + p * 192;
            hv[p] = h1l[e < 864 ? e : 863];
        }
#pragma unroll
        for (int p = 0; p < 5; ++p) {
            int e = tid + p * 192;
            if (e < 864) {
                uint4 u0, u1;
                spline_chunks(hv[p], u0, u1);
                int ch = e * 2;
                int q = (ch >> 3) & 7;
                feat[ch ^ q] = u0;
                feat[(ch + 1) ^ q] = u1;
            }
        }
    }
    __syncthreads();

    // ---- Phase D: conv2, 36 kc unrolled, 4-deep prefetch, dual chains ----
    {
        const int py = ln15 >> 2, px = ln15 & 3;
        const int epx = py * 24 + px * 2;           // (2py)*12 + 2px
        const int kk0 = wv * 36;
        const f16* bbase = W2g + ((kk0 * 2 + gt) * 16 + ln15) * 16 + gh * 8;
        f16x8 wreg[4];
#pragma unroll
        for (int i = 0; i < 4; ++i)
            wreg[i] = *(const f16x8*)(bbase + i * 512);

        f32x4 accA = {0, 0, 0, 0}, accB = {0, 0, 0, 0};

#pragma unroll
        for (int i = 0; i < 36; ++i) {
            f16x8 bcur = wreg[i & 3];
            wreg[i & 3] = *(const f16x8*)(bbase + (i + 4) * 512); // overread: ws pad
            int c = 2 * wv + (i / 18);              // i/18 literal after unroll
            int tk = i - (i / 18) * 18;
            int tap = tk * 2 + gt;
            int ey = (tap * 171) >> 10, ex = tap - ey * 6;
            int elem = c * 144 + epx + ey * 12 + ex;
            int ch = elem * 2 + gh;
            ch ^= (ch >> 3) & 7;
            f16x8 afrag = *(const f16x8*)(&feat[ch]);
            if ((i & 1) == 0)
                accA = __builtin_amdgcn_mfma_f32_16x16x32_f16(afrag, bcur, accA, 0, 0, 0);
            else
                accB = __builtin_amdgcn_mfma_f32_16x16x32_f16(afrag, bcur, accB, 0, 0, 0);
        }
        f32x4 acc = accA + accB;

        if (wv) rbuf[wv - 1][lane] = make_float4(acc[0], acc[1], acc[2], acc[3]);
        __syncthreads();
        if (wv == 0) {
            float4 r0 = rbuf[0][lane], r1 = rbuf[1][lane];
            *(float4*)&h2[img * 256 + ln15 * 16 + g * 4] =
                make_float4(acc[0] + r0.x + r1.x, acc[1] + r0.y + r1.y,
                            acc[2] + r0.z + r1.z, acc[3] + r0.w + r1.w);
        }
    }
}

// ---------------------------------------------------------------------------
// K3: fc1(relu) -> fc2(relu) -> fc3. Block = 2 batch rows, 256 threads,
// 512 blocks (2/CU). Weight rows L2-resident (183 KB total).
// ---------------------------------------------------------------------------
__global__ __launch_bounds__(256) void k_fc(
    const float* __restrict__ h2,
    const float* __restrict__ w1, const float* __restrict__ b1,
    const float* __restrict__ w2, const float* __restrict__ b2,
    const float* __restrict__ w3, const float* __restrict__ b3,
    float* __restrict__ out)
{
    __shared__ float xin[2][260];
    __shared__ float a1[2][120];
    __shared__ float a2[2][84];
    const int tid = threadIdx.x;
    const int r0 = blockIdx.x * 2;

    for (int i = tid; i < 512; i += 256)
        xin[i >> 8][i & 255] = h2[r0 * 256 + i];
    __syncthreads();

    if (tid < 240) {                  // 120 out x 2 rows
        const int o = tid >> 1, r = tid & 1;
        const float* w = w1 + o * 256;
        float s = 0.0f;
#pragma unroll 8
        for (int k = 0; k < 64; ++k) {
            float4 wv = ((const float4*)w)[k];
            float4 xv = *(const float4*)(&xin[r][k * 4]);
            s += wv.x * xv.x + wv.y * xv.y + wv.z * xv.z + wv.w * xv.w;
        }
        a1[r][o] = fmaxf(s + b1[o], 0.0f);
    }
    __syncthreads();

    if (tid < 168) {                  // 84 out x 2 rows
        const int o = tid >> 1, r = tid & 1;
        const float* w = w2 + o * 120;
        float s = 0.0f;
#pragma unroll
        for (int k = 0; k < 30; ++k) {
            float4 wv = ((const float4*)w)[k];
            float4 xv = *(const float4*)(&a1[r][k * 4]);
            s += wv.x * xv.x + wv.y * xv.y + wv.z * xv.z + wv.w * xv.w;
        }
        a2[r][o] = fmaxf(s + b2[o], 0.0f);
    }
    __syncthreads();

    if (tid < 124) {                  // 62 out x 2 rows
        const int o = tid >> 1, r = tid & 1;
        const float* w = w3 + o * 84;
        float s = 0.0f;
#pragma unroll
        for (int k = 0; k < 21; ++k) {
            float4 wv = ((const float4*)w)[k];
            float4 xv = *(const float4*)(&a2[r][k * 4]);
            s += wv.x * xv.x + wv.y * xv.y + wv.z * xv.z + wv.w * xv.w;
        }
        out[(r0 + r) * 62 + o] = s + b3[o];
    }
}

// ---------------------------------------------------------------------------
extern "C" void kernel_launch(void* const* d_in, const int* in_sizes, int n_in,
                              void* d_out, int out_size, void* d_ws, size_t ws_size,
                              hipStream_t stream)
{
    (void)in_sizes; (void)n_in; (void)out_size; (void)ws_size;
    const float* x      = (const float*)d_in[0];
    const float* c1_bw  = (const float*)d_in[1];
    const float* c1_sw  = (const float*)d_in[2];
    const float* c1_sc  = (const float*)d_in[3];
    const float* c2_bw  = (const float*)d_in[4];
    const float* c2_sw  = (const float*)d_in[5];
    const float* c2_sc  = (const float*)d_in[6];
    const float* fc1_w  = (const float*)d_in[7];
    const float* fc1_b  = (const float*)d_in[8];
    const float* fc2_w  = (const float*)d_in[9];
    const float* fc2_b  = (const float*)d_in[10];
    const float* fc3_w  = (const float*)d_in[11];
    const float* fc3_b  = (const float*)d_in[12];
    float* out = (float*)d_out;

    char* wsb = (char*)d_ws;
    f16*   W1g = (f16*)(wsb);                  //  9216 f16 = 18432 B
    f16*   W2g = (f16*)(wsb + 18432);          // 55296 f16 = 110592 B (+pad)
    float* h2  = (float*)(wsb + 131072);       // 1024*256 f32 (prefetch may
                                               // overread a few KB into here)

    hipLaunchKernelGGL(k_prep, dim3(256), dim3(256), 0, stream,
                       c1_bw, c1_sw, c1_sc, c2_bw, c2_sw, c2_sc, W1g, W2g);
    hipLaunchKernelGGL(k_conv12, dim3(1024), dim3(192), 0, stream,
                       x, W1g, W2g, h2);
    hipLaunchKernelGGL(k_fc, dim3(512), dim3(256), 0, stream,
                       h2, fc1_w, fc1_b, fc2_w, fc2_b, fc3_w, fc3_b, out);
}

// Round 12
// 39.119 us; speedup vs baseline: 1.1368x; 1.0124x over previous
//
#include <hip/hip_runtime.h>

// ---------------------------------------------------------------------------
// LeNet5-KAN on MI355X.  R12: per-wave PRIVATE staging regions remove the
// A->B and C->D barriers (only the h1 exchange barrier + reduce barrier
// remain). Wave wv stages input rows 8wv..8wv+11 (conv1 M-split) and h1
// channels 2wv,2wv+1 (conv2 K-split) privately; same-wave LDS ordering is
// HW-guaranteed (in-order DS pipe), no cross-wave feat deps.
// MFMA f16 in / f32 accum; avg-pool folded into weights (stride-2 conv6x6).
//
//   A-frag: lane&15 = out px, lane>>4 = k-group (16B ds_read_b128)
//   B-frag: lane&15 = o,     lane>>4 = same k-group (16B global load, L2)
//   C     : col = lane&15 (o), row = (lane>>4)*4 + reg
// feat LDS chunks (16B) XOR-swizzled: ch ^= (ch>>3)&7  (regions are 8-chunk
// aligned: 672, 576 -> swizzle never crosses a region boundary).
// ---------------------------------------------------------------------------

typedef _Float16 f16;
typedef f16 f16x8 __attribute__((ext_vector_type(8)));
typedef float f32x4 __attribute__((ext_vector_type(4)));

#define ONE_SIXTH 0.16666666666666666f

__device__ __forceinline__ void spline9(float v, float* __restrict__ f) {
    float u  = 2.5f * v + 5.5f;
    bool valid = (u >= 0.0f) && (u < 11.0f);
    float fi = floorf(u);
    int   i  = (int)fi;
    float w  = u - fi;
    float omw = 1.0f - w;
    float w2 = w * w, w3 = w2 * w;
    float c0 = omw * omw * omw * ONE_SIXTH;
    float c1 = (3.0f * w3 - 6.0f * w2 + 4.0f) * ONE_SIXTH;
    float c2 = (-3.0f * w3 + 3.0f * w2 + 3.0f * w + 1.0f) * ONE_SIXTH;
    float c3 = w3 * ONE_SIXTH;
    int j0 = i - 3;
#pragma unroll
    for (int j = 0; j < 8; ++j) {
        int d = j - j0;
        float val = (d == 0) ? c0 : (d == 1) ? c1 : (d == 2) ? c2 : (d == 3) ? c3 : 0.0f;
        f[j] = valid ? val : 0.0f;
    }
    f[8] = fmaxf(v, 0.0f);
}

// two 16B chunks: c0 = bases[0..7] as f16, c1 = {relu, 0 x7}
__device__ __forceinline__ void spline_chunks(float v, uint4& u0, uint4& u1) {
    float f[9];
    spline9(v, f);
    union { f16 h[8]; uint4 u; } a, b;
#pragma unroll
    for (int j = 0; j < 8; ++j) a.h[j] = (f16)f[j];
    b.u.x = 0u; b.u.y = 0u; b.u.z = 0u; b.u.w = 0u;
    b.h[0] = (f16)f[8];
    u0 = a.u; u1 = b.u;
}

// ---------------------------------------------------------------------------
// K0: build pooled-conv weights, f16 (unchanged from R9/R11).
// ---------------------------------------------------------------------------
__global__ __launch_bounds__(256) void k_prep(
    const float* __restrict__ c1_bw, const float* __restrict__ c1_sw,
    const float* __restrict__ c1_sc,
    const float* __restrict__ c2_bw, const float* __restrict__ c2_sw,
    const float* __restrict__ c2_sc,
    f16* __restrict__ W1g, f16* __restrict__ W2g)
{
    int t = blockIdx.x * 256 + threadIdx.x;
    if (t < 9216) {
        int tap = t >> 8, r = t & 255;
        int o = r >> 4, k = r & 15;
        float val = 0.0f;
        if (o < 6 && k < 9) {
            int ey = tap / 6, ex = tap - 6 * ey;
            float s = 0.0f;
            for (int a = 0; a < 2; ++a) {
                for (int b = 0; b < 2; ++b) {
                    int dy = ey - a, dx = ex - b;
                    if (dy >= 0 && dy < 5 && dx >= 0 && dx < 5) {
                        int idx = o * 25 + dy * 5 + dx;
                        s += (k == 8) ? c1_bw[idx] : c1_sw[idx * 8 + k] * c1_sc[idx];
                    }
                }
            }
            val = 0.25f * s;
        }
        W1g[t] = (f16)val;
    }
    if (t < 55296) {
        int c = t / 9216, r = t - c * 9216;
        int tap = r >> 8, rr = r & 255;
        int o = rr >> 4, k = rr & 15;
        float val = 0.0f;
        if (k < 9) {
            int ey = tap / 6, ex = tap - 6 * ey;
            float s = 0.0f;
            for (int a = 0; a < 2; ++a) {
                for (int b = 0; b < 2; ++b) {
                    int dy = ey - a, dx = ex - b;
                    if (dy >= 0 && dy < 5 && dx >= 0 && dx < 5) {
                        int idx = o * 150 + c * 25 + dy * 5 + dx;
                        s += (k == 8) ? c2_bw[idx] : c2_sw[idx * 8 + k] * c2_sc[idx];
                    }
                }
            }
            val = 0.25f * s;
        }
        W2g[t] = (f16)val;
    }
}

// ---------------------------------------------------------------------------
// K1: fused conv1+pool -> conv2+pool. One block = 1 image, 192 thr = 3 waves.
// A(priv): wave stages its 12 input rows -> featA[wv*672 ..].
// B: conv1 MFMA (reads own region only) -> h1l (shared).   == barrier ==
// C(priv): wave stages h1 channels 2wv,2wv+1 -> featC[wv*576 ..].
// D: conv2 MFMA (own region, K-split) -> rbuf.             == barrier ==
// reduce -> h2.
// ---------------------------------------------------------------------------
__global__ __launch_bounds__(192, 3) void k_conv12(
    const float* __restrict__ x, const f16* __restrict__ W1g,
    const f16* __restrict__ W2g, float* __restrict__ h2)
{
    __shared__ uint4  feat[2016];    // A: [3][672]; C: [3][576] (aliased)
    __shared__ float  h1l[864];      // conv1 output [o][144] f32
    __shared__ float4 rbuf[2][64];   // conv2 partial sums (waves 1,2)

    const int img = blockIdx.x;
    const int tid = threadIdx.x;
    const int lane = tid & 63, wv = tid >> 6;
    const int ln15 = lane & 15, g = lane >> 4;
    const int gh = g & 1, gt = g >> 1;

    // ---- Phase A (private): stage rows 8wv..8wv+11 of x ----
    {
        const int r0 = 8 * wv;
        float xv[6];
#pragma unroll
        for (int p = 0; p < 6; ++p) {
            int e = lane + p * 64;
            int ee = e < 336 ? e : 335;
            int row = ee / 28, col = ee - row * 28;
            xv[p] = x[img * 784 + (r0 + row) * 28 + col];
        }
#pragma unroll
        for (int p = 0; p < 6; ++p) {
            int e = lane + p * 64;
            if (e < 336) {
                uint4 u0, u1;
                spline_chunks(xv[p], u0, u1);
                int ch = wv * 672 + e * 2;
                int q = (ch >> 3) & 7;
                feat[ch ^ q] = u0;
                feat[(ch + 1) ^ q] = u1;
            }
        }
    }
    // no barrier: B reads only this wave's region (in-order DS pipe)

    // ---- Phase B: conv1, 18 kc unrolled, 4-deep prefetch ----
    {
        int ebase[3];
#pragma unroll
        for (int t = 0; t < 3; ++t) {
            int p = (wv * 3 + t) * 16 + ln15;
            int py = p / 12, px = p - py * 12;
            int row_local = 2 * py - 8 * wv;        // 0,2,4,6
            ebase[t] = row_local * 28 + 2 * px;
        }
        const f16* bbase = W1g + (gt * 16 + ln15) * 16 + gh * 8;  // + kc*512
        f16x8 wreg[4];
#pragma unroll
        for (int i = 0; i < 4; ++i)
            wreg[i] = *(const f16x8*)(bbase + i * 512);

        f32x4 acc[3] = {{0,0,0,0},{0,0,0,0},{0,0,0,0}};

#pragma unroll
        for (int kc = 0; kc < 18; ++kc) {
            f16x8 bcur = wreg[kc & 3];
            wreg[kc & 3] = *(const f16x8*)(bbase + (kc + 4) * 512); // overreads into W2g: safe
            int tap = kc * 2 + gt;
            int ey = (tap * 171) >> 10, ex = tap - ey * 6;
            int eoff = ey * 28 + ex;
#pragma unroll
            for (int t = 0; t < 3; ++t) {
                int ch = wv * 672 + (ebase[t] + eoff) * 2 + gh;
                ch ^= (ch >> 3) & 7;
                f16x8 afrag = *(const f16x8*)(&feat[ch]);
                acc[t] = __builtin_amdgcn_mfma_f32_16x16x32_f16(afrag, bcur, acc[t], 0, 0, 0);
            }
        }
        if (ln15 < 6) {
#pragma unroll
            for (int t = 0; t < 3; ++t) {
                int p0 = (wv * 3 + t) * 16 + g * 4;     // row = g*4 + reg
                *(float4*)&h1l[ln15 * 144 + p0] =
                    make_float4(acc[t][0], acc[t][1], acc[t][2], acc[t][3]);
            }
        }
    }
    __syncthreads();    // h1l exchange + featA->featC alias protection

    // ---- Phase C (private): stage h1 channels 2wv, 2wv+1 ----
    {
        float hv[5];
#pragma unroll
        for (int p = 0; p < 5; ++p) {
            int e = lane + p * 64;
            int ee = e < 288 ? e : 287;
            hv[p] = h1l[wv * 288 + ee];         // h1l[(2wv)*144 + e]
        }
#pragma unroll
        for (int p = 0; p < 5; ++p) {
            int e = lane + p * 64;
            if (e < 288) {
                uint4 u0, u1;
                spline_chunks(hv[p], u0, u1);
                int ch = wv * 576 + e * 2;
                int q = (ch >> 3) & 7;
                feat[ch ^ q] = u0;
                feat[(ch + 1) ^ q] = u1;
            }
        }
    }
    // no barrier: D reads only this wave's region

    // ---- Phase D: conv2, K split over 3 waves, 4-deep prefetch, dual acc ----
    {
        const int py = ln15 >> 2, px = ln15 & 3;
        const int epx = py * 24 + px * 2;           // (2py)*12 + 2px
        const int kk0 = wv * 36;
        const f16* bbase = W2g + ((kk0 * 2 + gt) * 16 + ln15) * 16 + gh * 8;
        f16x8 wreg[4];
#pragma unroll
        for (int i = 0; i < 4; ++i)
            wreg[i] = *(const f16x8*)(bbase + i * 512);

        f32x4 accA = {0, 0, 0, 0}, accB = {0, 0, 0, 0};

#pragma unroll
        for (int i = 0; i < 36; ++i) {
            f16x8 bcur = wreg[i & 3];
            wreg[i & 3] = *(const f16x8*)(bbase + (i + 4) * 512); // overread: ws pad
            int cl = i / 18;                        // 0/1, literal after unroll
            int tk = i - cl * 18;
            int tap = tk * 2 + gt;
            int ey = (tap * 171) >> 10, ex = tap - ey * 6;
            int elem = cl * 144 + epx + ey * 12 + ex;
            int ch = wv * 576 + elem * 2 + gh;
            ch ^= (ch >> 3) & 7;
            f16x8 afrag = *(const f16x8*)(&feat[ch]);
            if ((i & 1) == 0)
                accA = __builtin_amdgcn_mfma_f32_16x16x32_f16(afrag, bcur, accA, 0, 0, 0);
            else
                accB = __builtin_amdgcn_mfma_f32_16x16x32_f16(afrag, bcur, accB, 0, 0, 0);
        }
        f32x4 acc = accA + accB;

        if (wv) rbuf[wv - 1][lane] = make_float4(acc[0], acc[1], acc[2], acc[3]);
        __syncthreads();
        if (wv == 0) {
            float4 r0 = rbuf[0][lane], r1 = rbuf[1][lane];
            *(float4*)&h2[img * 256 + ln15 * 16 + g * 4] =
                make_float4(acc[0] + r0.x + r1.x, acc[1] + r0.y + r1.y,
                            acc[2] + r0.z + r1.z, acc[3] + r0.w + r1.w);
        }
    }
}

// ---------------------------------------------------------------------------
// K3: fc1(relu) -> fc2(relu) -> fc3. Block = 4 batch rows, 256 threads,
// 256 blocks (1/CU, all CUs busy; halved L2 weight traffic vs 512 blocks).
// ---------------------------------------------------------------------------
__global__ __launch_bounds__(256) void k_fc(
    const float* __restrict__ h2,
    const float* __restrict__ w1, const float* __restrict__ b1,
    const float* __restrict__ w2, const float* __restrict__ b2,
    const float* __restrict__ w3, const float* __restrict__ b3,
    float* __restrict__ out)
{
    __shared__ float xin[4][260];
    __shared__ float a1[4][120];
    __shared__ float a2[4][84];
    const int tid = threadIdx.x;
    const int r0 = blockIdx.x * 4;

    for (int i = tid; i < 1024; i += 256)
        xin[i >> 8][i & 255] = h2[r0 * 256 + i];
    __syncthreads();

    for (int idx = tid; idx < 480; idx += 256) {      // 120 out x 4 rows
        const int o = idx >> 2, r = idx & 3;
        const float* w = w1 + o * 256;
        float s = 0.0f;
#pragma unroll 8
        for (int k = 0; k < 64; ++k) {
            float4 wv = ((const float4*)w)[k];
            float4 xv = *(const float4*)(&xin[r][k * 4]);
            s += wv.x * xv.x + wv.y * xv.y + wv.z * xv.z + wv.w * xv.w;
        }
        a1[r][o] = fmaxf(s + b1[o], 0.0f);
    }
    __syncthreads();

    for (int idx = tid; idx < 336; idx += 256) {      // 84 out x 4 rows
        const int o = idx >> 2, r = idx & 3;
        const float* w = w2 + o * 120;
        float s = 0.0f;
#pragma unroll
        for (int k = 0; k < 30; ++k) {
            float4 wv = ((const float4*)w)[k];
            float4 xv = *(const float4*)(&a1[r][k * 4]);
            s += wv.x * xv.x + wv.y * xv.y + wv.z * xv.z + wv.w * xv.w;
        }
        a2[r][o] = fmaxf(s + b2[o], 0.0f);
    }
    __syncthreads();

    for (int idx = tid; idx < 248; idx += 256) {      // 62 out x 4 rows
        const int o = idx >> 2, r = idx & 3;
        const float* w = w3 + o * 84;
        float s = 0.0f;
#pragma unroll
        for (int k = 0; k < 21; ++k) {
            float4 wv = ((const float4*)w)[k];
            float4 xv = *(const float4*)(&a2[r][k * 4]);
            s += wv.x * xv.x + wv.y * xv.y + wv.z * xv.z + wv.w * xv.w;
        }
        out[(r0 + r) * 62 + o] = s + b3[o];
    }
}

// ---------------------------------------------------------------------------
extern "C" void kernel_launch(void* const* d_in, const int* in_sizes, int n_in,
                              void* d_out, int out_size, void* d_ws, size_t ws_size,
                              hipStream_t stream)
{
    (void)in_sizes; (void)n_in; (void)out_size; (void)ws_size;
    const float* x      = (const float*)d_in[0];
    const float* c1_bw  = (const float*)d_in[1];
    const float* c1_sw  = (const float*)d_in[2];
    const float* c1_sc  = (const float*)d_in[3];
    const float* c2_bw  = (const float*)d_in[4];
    const float* c2_sw  = (const float*)d_in[5];
    const float* c2_sc  = (const float*)d_in[6];
    const float* fc1_w  = (const float*)d_in[7];
    const float* fc1_b  = (const float*)d_in[8];
    const float* fc2_w  = (const float*)d_in[9];
    const float* fc2_b  = (const float*)d_in[10];
    const float* fc3_w  = (const float*)d_in[11];
    const float* fc3_b  = (const float*)d_in[12];
    float* out = (float*)d_out;

    char* wsb = (char*)d_ws;
    f16*   W1g = (f16*)(wsb);                  //  9216 f16 = 18432 B
    f16*   W2g = (f16*)(wsb + 18432);          // 55296 f16 = 110592 B
    float* h2  = (float*)(wsb + 139264);       // 1024*256 f32 (8KB pad after
                                               // W2g for prefetch overread)

    hipLaunchKernelGGL(k_prep, dim3(256), dim3(256), 0, stream,
                       c1_bw, c1_sw, c1_sc, c2_bw, c2_sw, c2_sc, W1g, W2g);
    hipLaunchKernelGGL(k_conv12, dim3(1024), dim3(192), 0, stream,
                       x, W1g, W2g, h2);
    hipLaunchKernelGGL(k_fc, dim3(256), dim3(256), 0, stream,
                       h2, fc1_w, fc1_b, fc2_w, fc2_b, fc3_w, fc3_b, out);
}